// Round 1
// baseline (2241.376 us; speedup 1.0000x reference)
//
#include <hip/hip_runtime.h>
#include <math.h>

#define N_TOT 8400
#define MASK_WORDS 132   // ceil(8400/64)

__device__ __constant__ float kScoreT = 0.5f;
__device__ __constant__ float kNmsT = 0.4f;

// ---------------- K1: decode all 3 scales -> logit, sigmoid, boxes, kps ----------------
__global__ void decode_kernel(const float* __restrict__ score0, const float* __restrict__ bbox0, const float* __restrict__ kps0,
                              const float* __restrict__ score1, const float* __restrict__ bbox1, const float* __restrict__ kps1,
                              const float* __restrict__ score2, const float* __restrict__ bbox2, const float* __restrict__ kps2,
                              float* __restrict__ logit, float* __restrict__ sig,
                              float* __restrict__ box, float* __restrict__ kps) {
    int i = blockIdx.x * blockDim.x + threadIdx.x;
    if (i >= N_TOT) return;
    const float *sc, *bb, *kp;
    int m, F; float s;
    if (i < 6400)      { sc = score0; bb = bbox0; kp = kps0; m = i;        F = 80; s = 8.f;  }
    else if (i < 8000) { sc = score1; bb = bbox1; kp = kps1; m = i - 6400; F = 40; s = 16.f; }
    else               { sc = score2; bb = bbox2; kp = kps2; m = i - 8000; F = 20; s = 32.f; }
    float px = (float)(m % F) * s;
    float py = (float)(m / F) * s;
    float lg = sc[m];
    logit[i] = lg;
    sig[i] = 1.0f / (1.0f + expf(-lg));
    float d0 = bb[m*4+0]*s, d1 = bb[m*4+1]*s, d2 = bb[m*4+2]*s, d3 = bb[m*4+3]*s;
    box[i*4+0] = px - d0;
    box[i*4+1] = py - d1;
    box[i*4+2] = px + d2;
    box[i*4+3] = py + d3;
    #pragma unroll
    for (int c = 0; c < 5; ++c) {
        kps[i*10 + 2*c]   = px + kp[m*10 + 2*c]   * s;
        kps[i*10 + 2*c+1] = py + kp[m*10 + 2*c+1] * s;
    }
}

// ---------------- K2: exact rank (descending logit, index tie-break) ----------------
// rank[i] = #{ j : logit[j] > logit[i]  ||  (logit[j] == logit[i] && j < i) }
// This is exactly stable argsort(-scores) since sigmoid (in f64 ref) is strictly monotone.
__global__ void rank_kernel(const float* __restrict__ logit, int* __restrict__ rank) {
    __shared__ float tile[256];
    int i = blockIdx.x * 256 + threadIdx.x;
    float li = (i < N_TOT) ? logit[i] : 0.f;
    int rk = 0;
    for (int t0 = 0; t0 < N_TOT; t0 += 256) {
        int j = t0 + threadIdx.x;
        tile[threadIdx.x] = (j < N_TOT) ? logit[j] : -1e30f;
        __syncthreads();
        int lim = min(256, N_TOT - t0);
        for (int k = 0; k < lim; ++k) {
            float lj = tile[k];
            int j2 = t0 + k;
            bool before = (lj > li) || (lj == li && j2 < i);
            rk += before ? 1 : 0;
        }
        __syncthreads();
    }
    if (i < N_TOT) rank[i] = rk;
}

// ---------------- K3: scatter into sorted order ----------------
__global__ void scatter_kernel(const int* __restrict__ rank,
                               const float* __restrict__ logit, const float* __restrict__ sig,
                               const float* __restrict__ box, const float* __restrict__ kps,
                               float* __restrict__ s_logit, float* __restrict__ s_sig,
                               float* __restrict__ s_box, float* __restrict__ s_kps) {
    int i = blockIdx.x * blockDim.x + threadIdx.x;
    if (i >= N_TOT) return;
    int r = rank[i];
    s_logit[r] = logit[i];
    s_sig[r] = sig[i];
    #pragma unroll
    for (int c = 0; c < 4; ++c)  s_box[r*4+c] = box[i*4+c];
    #pragma unroll
    for (int c = 0; c < 10; ++c) s_kps[r*10+c] = kps[i*10+c];
}

// ---------------- K4: successor-overlap bitmask matrix ----------------
// mask[r][cw] bit k set iff j = cw*64+k satisfies: j > r, both valid (logit>0), IoU > 0.4
__global__ __launch_bounds__(64) void mask_kernel(const float* __restrict__ s_logit,
                                                  const float* __restrict__ s_box,
                                                  unsigned long long* __restrict__ mask) {
    int cw = blockIdx.x;   // column word index 0..131
    int rb = blockIdx.y;   // row block 0..131
    int tid = threadIdx.x; // 0..63
    int r = rb * 64 + tid;

    __shared__ float cbx1[64], cby1[64], cbx2[64], cby2[64], carea[64];
    int j0 = cw * 64;
    int j = j0 + tid;
    float x1 = 0.f, y1 = 0.f, x2 = 0.f, y2 = 0.f, lgj = -1.f;
    if (j < N_TOT) {
        x1 = s_box[j*4+0]; y1 = s_box[j*4+1]; x2 = s_box[j*4+2]; y2 = s_box[j*4+3];
        lgj = s_logit[j];
    }
    cbx1[tid] = x1; cby1[tid] = y1; cbx2[tid] = x2; cby2[tid] = y2;
    carea[tid] = (x2 - x1) * (y2 - y1);
    unsigned long long cvalid = __ballot(j < N_TOT && lgj > 0.f);
    __syncthreads();

    if (r >= N_TOT) return;
    unsigned long long bits = 0ull;
    float lgr = s_logit[r];
    if (lgr > 0.f && (j0 + 63) > r) {  // row valid and column range contains successors
        float rx1 = s_box[r*4+0], ry1 = s_box[r*4+1], rx2 = s_box[r*4+2], ry2 = s_box[r*4+3];
        float rarea = (rx2 - rx1) * (ry2 - ry1);
        for (int k = 0; k < 64; ++k) {
            int jj = j0 + k;
            if (jj <= r) continue;
            if (!((cvalid >> k) & 1ull)) continue;
            float ltx = fmaxf(rx1, cbx1[k]);
            float lty = fmaxf(ry1, cby1[k]);
            float rbx = fminf(rx2, cbx2[k]);
            float rby = fminf(ry2, cby2[k]);
            float w = fmaxf(rbx - ltx, 0.f);
            float h = fmaxf(rby - lty, 0.f);
            float inter = w * h;
            float iou = inter / (rarea + carea[k] - inter + 1e-9f);
            if (iou > 0.4f) bits |= (1ull << k);
        }
    }
    mask[(size_t)r * MASK_WORDS + cw] = bits;
}

// ---------------- K5: serial greedy NMS resolve (one wave) ----------------
// removed-bit of row r is final by step r (masks only hold successors), so
// final keep = valid & ~removed. Rows prefetched D deep; decision broadcast
// via v_readlane (wave-uniform branch).
__global__ __launch_bounds__(64) void nms_kernel(const float* __restrict__ s_logit,
                                                 const unsigned long long* __restrict__ mask,
                                                 unsigned long long* __restrict__ keep_words) {
    int lane = threadIdx.x;
    // Build valid words (lane owns words lane, 64+lane, 128+lane) and count V.
    unsigned long long validw[3] = {0ull, 0ull, 0ull};
    int V = 0;
    for (int w = 0; w < MASK_WORDS; ++w) {
        int idx = w * 64 + lane;
        float lg = (idx < N_TOT) ? s_logit[idx] : -1.f;
        unsigned long long vw = __ballot(lg > 0.f);
        V += (int)__popcll(vw) / 64 * 0;  // (avoid compiler confusion) -- real add below
        V += 0;
        if ((w & 63) == lane) validw[w >> 6] = vw;
        // accumulate V (same value on all lanes)
        V += (lane == lane) ? (int)__popcll(vw) : 0;
    }

    unsigned long long rem[3] = {0ull, 0ull, 0ull};
    const int D = 4;
    unsigned long long buf0[D], buf1[D], buf2[D];

    auto loadrow = [&](int r, int d) {
        const unsigned long long* row = mask + (size_t)r * MASK_WORDS;
        buf0[d] = row[lane];
        buf1[d] = row[64 + lane];
        buf2[d] = (lane < 4) ? row[128 + lane] : 0ull;
    };
    for (int d = 0; d < D; ++d) {
        int rr = (V > 0) ? min(d, V - 1) : 0;
        loadrow(rr, d);
    }

    for (int r = 0; r < V; ++r) {
        int d = r & (D - 1);
        int w = r >> 6;
        int slot = w >> 6;       // 0,1,2 (wave-uniform)
        int owner = w & 63;
        int b = r & 63;
        unsigned long long remw;
        if (slot == 0) remw = rem[0];
        else if (slot == 1) remw = rem[1];
        else remw = rem[2];
        unsigned int half = (b < 32) ? (unsigned int)(remw & 0xffffffffull)
                                     : (unsigned int)(remw >> 32);
        unsigned int word = (unsigned int)__builtin_amdgcn_readlane((int)half, owner);
        bool kept = ((word >> (b & 31)) & 1u) == 0u;
        if (kept) {
            rem[0] |= buf0[d];
            rem[1] |= buf1[d];
            rem[2] |= buf2[d];
        }
        int pr = r + D;
        if (pr < V) loadrow(pr, d);
    }

    // keep = valid & ~removed
    #pragma unroll
    for (int s = 0; s < 3; ++s) {
        int w = s * 64 + lane;
        if (w < MASK_WORDS) keep_words[w] = validw[s] & ~rem[s];
    }
}

// ---------------- K6: write outputs ----------------
// out layout: boxes[8400*4] | scores[8400] | kps[8400*10] | keep[8400]
__global__ void output_kernel(const float* __restrict__ s_sig, const float* __restrict__ s_box,
                              const float* __restrict__ s_kps,
                              const unsigned long long* __restrict__ keep_words,
                              float* __restrict__ out) {
    int r = blockIdx.x * blockDim.x + threadIdx.x;
    if (r >= N_TOT) return;
    float m = ((keep_words[r >> 6] >> (r & 63)) & 1ull) ? 1.0f : 0.0f;
    float* ob = out;                   // 8400*4
    float* os = out + 33600;           // 8400
    float* okp = out + 42000;          // 8400*10
    float* om = out + 126000;          // 8400
    #pragma unroll
    for (int c = 0; c < 4; ++c)  ob[r*4+c] = s_box[r*4+c] * m;
    os[r] = s_sig[r] * m;
    #pragma unroll
    for (int c = 0; c < 10; ++c) okp[r*10+c] = s_kps[r*10+c] * m;
    om[r] = m;
}

extern "C" void kernel_launch(void* const* d_in, const int* in_sizes, int n_in,
                              void* d_out, int out_size, void* d_ws, size_t ws_size,
                              hipStream_t stream) {
    // Inputs in setup_inputs() dict order: score0,bbox0,kps0,score1,bbox1,kps1,score2,bbox2,kps2
    // Defensive: if position 1 isn't bbox0 (25600), fall back to signature order.
    const float *score0, *bbox0, *kps0, *score1, *bbox1, *kps1, *score2, *bbox2, *kps2;
    if (in_sizes[1] == 25600) {
        score0 = (const float*)d_in[0]; bbox0 = (const float*)d_in[1]; kps0 = (const float*)d_in[2];
        score1 = (const float*)d_in[3]; bbox1 = (const float*)d_in[4]; kps1 = (const float*)d_in[5];
        score2 = (const float*)d_in[6]; bbox2 = (const float*)d_in[7]; kps2 = (const float*)d_in[8];
    } else {
        score0 = (const float*)d_in[0]; score1 = (const float*)d_in[1]; score2 = (const float*)d_in[2];
        bbox0  = (const float*)d_in[3]; bbox1  = (const float*)d_in[4]; bbox2  = (const float*)d_in[5];
        kps0   = (const float*)d_in[6]; kps1   = (const float*)d_in[7]; kps2   = (const float*)d_in[8];
    }

    char* ws = (char*)d_ws;
    float* logit   = (float*)(ws + 0);        // 33600 B
    float* sig     = (float*)(ws + 33600);    // 33600 B
    float* box     = (float*)(ws + 67200);    // 134400 B
    float* kps     = (float*)(ws + 201600);   // 336000 B
    int*   rank    = (int*)  (ws + 537600);   // 33600 B
    float* s_logit = (float*)(ws + 571200);   // 33600 B
    float* s_sig   = (float*)(ws + 604800);   // 33600 B
    float* s_box   = (float*)(ws + 638400);   // 134400 B
    float* s_kps   = (float*)(ws + 772800);   // 336000 B -> ends 1108800
    unsigned long long* keep_words = (unsigned long long*)(ws + 1108800); // 1056 B
    unsigned long long* mask = (unsigned long long*)(ws + 1110144);      // 8.87 MB -> ~9.99 MB total

    float* out = (float*)d_out;

    decode_kernel<<<(N_TOT + 255) / 256, 256, 0, stream>>>(
        score0, bbox0, kps0, score1, bbox1, kps1, score2, bbox2, kps2,
        logit, sig, box, kps);
    rank_kernel<<<33, 256, 0, stream>>>(logit, rank);
    scatter_kernel<<<33, 256, 0, stream>>>(rank, logit, sig, box, kps,
                                           s_logit, s_sig, s_box, s_kps);
    mask_kernel<<<dim3(MASK_WORDS, MASK_WORDS), 64, 0, stream>>>(s_logit, s_box, mask);
    nms_kernel<<<1, 64, 0, stream>>>(s_logit, mask, keep_words);
    output_kernel<<<33, 256, 0, stream>>>(s_sig, s_box, s_kps, keep_words, out);
}

// Round 2
// 321.318 us; speedup vs baseline: 6.9756x; 6.9756x over previous
//
#include <hip/hip_runtime.h>
#include <math.h>

#define N_TOT 8400
#define MASK_WORDS 132   // ceil(8400/64)
#define CAP 32           // max (word,bits) entries per row
#define LDSN 1024        // rows preloaded into LDS in nms
#define EC 2             // entries per row preloaded into LDS

typedef unsigned long long u64;

// ---------------- K1: decode all 3 scales -> logit, sigmoid, boxes, kps ----------------
__global__ void decode_kernel(const float* __restrict__ score0, const float* __restrict__ bbox0, const float* __restrict__ kps0,
                              const float* __restrict__ score1, const float* __restrict__ bbox1, const float* __restrict__ kps1,
                              const float* __restrict__ score2, const float* __restrict__ bbox2, const float* __restrict__ kps2,
                              float* __restrict__ logit, float* __restrict__ sig,
                              float* __restrict__ box, float* __restrict__ kps) {
    int i = blockIdx.x * blockDim.x + threadIdx.x;
    if (i >= N_TOT) return;
    const float *sc, *bb, *kp;
    int m, F; float s;
    if (i < 6400)      { sc = score0; bb = bbox0; kp = kps0; m = i;        F = 80; s = 8.f;  }
    else if (i < 8000) { sc = score1; bb = bbox1; kp = kps1; m = i - 6400; F = 40; s = 16.f; }
    else               { sc = score2; bb = bbox2; kp = kps2; m = i - 8000; F = 20; s = 32.f; }
    float px = (float)(m % F) * s;
    float py = (float)(m / F) * s;
    float lg = sc[m];
    logit[i] = lg;
    sig[i] = 1.0f / (1.0f + expf(-lg));
    float d0 = bb[m*4+0]*s, d1 = bb[m*4+1]*s, d2 = bb[m*4+2]*s, d3 = bb[m*4+3]*s;
    box[i*4+0] = px - d0;
    box[i*4+1] = py - d1;
    box[i*4+2] = px + d2;
    box[i*4+3] = py + d3;
    #pragma unroll
    for (int c = 0; c < 5; ++c) {
        kps[i*10 + 2*c]   = px + kp[m*10 + 2*c]   * s;
        kps[i*10 + 2*c+1] = py + kp[m*10 + 2*c+1] * s;
    }
}

// ---------------- K2: exact rank (descending logit, index tie-break) ----------------
__global__ void rank_kernel(const float* __restrict__ logit, int* __restrict__ rank) {
    __shared__ float tile[256];
    int i = blockIdx.x * 256 + threadIdx.x;
    float li = (i < N_TOT) ? logit[i] : 0.f;
    int rk = 0;
    for (int t0 = 0; t0 < N_TOT; t0 += 256) {
        int j = t0 + threadIdx.x;
        tile[threadIdx.x] = (j < N_TOT) ? logit[j] : -1e30f;
        __syncthreads();
        int lim = min(256, N_TOT - t0);
        for (int k = 0; k < lim; ++k) {
            float lj = tile[k];
            int j2 = t0 + k;
            bool before = (lj > li) || (lj == li && j2 < i);
            rk += before ? 1 : 0;
        }
        __syncthreads();
    }
    if (i < N_TOT) rank[i] = rk;
}

// ---------------- K3: scatter into sorted order ----------------
__global__ void scatter_kernel(const int* __restrict__ rank,
                               const float* __restrict__ logit, const float* __restrict__ sig,
                               const float* __restrict__ box, const float* __restrict__ kps,
                               float* __restrict__ s_logit, float* __restrict__ s_sig,
                               float* __restrict__ s_box, float* __restrict__ s_kps) {
    int i = blockIdx.x * blockDim.x + threadIdx.x;
    if (i >= N_TOT) return;
    int r = rank[i];
    s_logit[r] = logit[i];
    s_sig[r] = sig[i];
    #pragma unroll
    for (int c = 0; c < 4; ++c)  s_box[r*4+c] = box[i*4+c];
    #pragma unroll
    for (int c = 0; c < 10; ++c) s_kps[r*10+c] = kps[i*10+c];
}

// ---------------- K3b: prep — valid words, zero rowflag + cnt ----------------
__global__ __launch_bounds__(64) void prep_kernel(const float* __restrict__ s_logit,
                                                  u64* __restrict__ validw,
                                                  u64* __restrict__ rowflag,
                                                  unsigned int* __restrict__ cnt) {
    int b = blockIdx.x;           // 0..131
    int lane = threadIdx.x;
    int idx = b * 64 + lane;
    float lg = (idx < N_TOT) ? s_logit[idx] : -1.f;
    u64 vw = __ballot(lg > 0.f);
    if (lane == 0) { validw[b] = vw; rowflag[b] = 0ull; }
    if (idx < N_TOT) cnt[idx] = 0u;
}

// ---------------- K4: sparse successor-overlap pairs ----------------
// For each row r, append entries (column word cw, bits) where bit k means
// j=cw*64+k is a valid successor with IoU>0.4. Rows with >=1 entry flagged.
__global__ __launch_bounds__(64) void pairs_kernel(const float* __restrict__ s_logit,
                                                   const float* __restrict__ s_box,
                                                   unsigned int* __restrict__ cnt,
                                                   ulonglong2* __restrict__ ent,
                                                   u64* __restrict__ rowflag) {
    int cw = blockIdx.x;   // column word 0..131
    int rb = blockIdx.y;   // row block 0..131
    if (cw < rb) return;   // all j <= r in these blocks
    int tid = threadIdx.x;

    __shared__ float cbx1[64], cby1[64], cbx2[64], cby2[64], carea[64];
    int j0 = cw * 64;
    int j = j0 + tid;
    float x1 = 0.f, y1 = 0.f, x2 = 0.f, y2 = 0.f, lgj = -1.f;
    if (j < N_TOT) {
        x1 = s_box[j*4+0]; y1 = s_box[j*4+1]; x2 = s_box[j*4+2]; y2 = s_box[j*4+3];
        lgj = s_logit[j];
    }
    cbx1[tid] = x1; cby1[tid] = y1; cbx2[tid] = x2; cby2[tid] = y2;
    carea[tid] = (x2 - x1) * (y2 - y1);
    u64 cvalid = __ballot(j < N_TOT && lgj > 0.f);
    __syncthreads();
    if (cvalid == 0ull) return;     // no valid columns (sorted => ranks >= V)

    int r = rb * 64 + tid;
    if (r >= N_TOT) return;
    float lgr = s_logit[r];
    if (lgr <= 0.f) return;

    float rx1 = s_box[r*4+0], ry1 = s_box[r*4+1], rx2 = s_box[r*4+2], ry2 = s_box[r*4+3];
    float rarea = (rx2 - rx1) * (ry2 - ry1);
    u64 bits = 0ull;
    for (int k = 0; k < 64; ++k) {
        int jj = j0 + k;
        if (jj <= r) continue;
        if (!((cvalid >> k) & 1ull)) continue;
        float ltx = fmaxf(rx1, cbx1[k]);
        float lty = fmaxf(ry1, cby1[k]);
        float rbx = fminf(rx2, cbx2[k]);
        float rby = fminf(ry2, cby2[k]);
        float w = fmaxf(rbx - ltx, 0.f);
        float h = fmaxf(rby - lty, 0.f);
        float inter = w * h;
        float iou = inter / (rarea + carea[k] - inter + 1e-9f);
        if (iou > 0.4f) bits |= (1ull << k);
    }
    if (bits) {
        unsigned idx = atomicAdd(&cnt[r], 1u);
        if (idx < CAP) {
            ulonglong2 e; e.x = bits; e.y = (u64)cw;
            ent[(size_t)r * CAP + idx] = e;
        }
        atomicOr(&rowflag[r >> 6], 1ull << (r & 63));
    }
}

// ---------------- K5: serial greedy resolve over SPARSE rows (one wave) ----------------
__global__ __launch_bounds__(64) void nms_kernel(const u64* __restrict__ rowflag_g,
                                                 const u64* __restrict__ validw_g,
                                                 const unsigned int* __restrict__ cnt_g,
                                                 const ulonglong2* __restrict__ ent_g,
                                                 u64* __restrict__ keep_words) {
    __shared__ unsigned short list[8448];   // nonzero rows, sorted ascending
    __shared__ unsigned int   lcnt[LDSN];
    __shared__ ulonglong2     lent[LDSN * EC];
    int lane = threadIdx.x;

    u64 rf[3], vw[3];
    #pragma unroll
    for (int s = 0; s < 3; ++s) {
        int w = s * 64 + lane;
        rf[s] = (w < MASK_WORDS) ? rowflag_g[w] : 0ull;
        vw[s] = (w < MASK_WORDS) ? validw_g[w] : 0ull;
    }

    // Build sorted nonzero-row list via wave prefix sums (3 slot phases).
    int base = 0;
    #pragma unroll
    for (int s = 0; s < 3; ++s) {
        int c = (int)__popcll(rf[s]);
        int x = c;
        #pragma unroll
        for (int o = 1; o < 64; o <<= 1) { int y = __shfl_up(x, o); if (lane >= o) x += y; }
        int excl = x - c;
        int total = __shfl(x, 63);
        int off = base + excl;
        u64 t = rf[s];
        int wbase = (s * 64 + lane) << 6;
        while (t) {
            int b = __builtin_ctzll(t); t &= t - 1;
            list[off++] = (unsigned short)(wbase | b);
        }
        base += total;
    }
    int n_nz = base;
    __syncthreads();

    // Preload cnt + first EC entries per listed row into LDS (parallel).
    int kcap = min(n_nz, LDSN);
    for (int k = lane; k < kcap; k += 64) {
        int r = list[k];
        unsigned c = cnt_g[r];
        lcnt[k] = c;
        unsigned cc = min(c, (unsigned)EC);
        for (unsigned e = 0; e < cc; ++e) lent[k * EC + e] = ent_g[(size_t)r * CAP + e];
    }
    __syncthreads();

    u64 rem[3] = {0ull, 0ull, 0ull};

    // depth-2 pipelined serial loop over LDS-resident rows
    int r_n = 0; unsigned c_n = 0; ulonglong2 e_n; e_n.x = 0; e_n.y = 0;
    if (kcap > 0) {
        r_n = list[0];
        c_n = lcnt[0];
        if (lane < EC) e_n = lent[lane];
    }
    for (int k = 0; k < kcap; ++k) {
        int r = r_n; unsigned c = c_n; ulonglong2 ee = e_n;
        int kn = k + 1;
        if (kn < kcap) {
            r_n = list[kn];
            c_n = lcnt[kn];
            if (lane < EC) e_n = lent[kn * EC + lane];
        }
        int w = r >> 6, slot = w >> 6, owner = w & 63, b = r & 63;
        u64 remw = (slot == 0) ? rem[0] : ((slot == 1) ? rem[1] : rem[2]);
        unsigned sel = (b < 32) ? (unsigned)remw : (unsigned)(remw >> 32);
        unsigned word = (unsigned)__builtin_amdgcn_readlane((int)sel, owner);
        if (!((word >> (b & 31)) & 1u)) {
            int cc = (int)min(c, (unsigned)EC);
            for (int e = 0; e < cc; ++e) {
                unsigned ew  = (unsigned)__builtin_amdgcn_readlane((int)(unsigned)ee.y, e);
                unsigned blo = (unsigned)__builtin_amdgcn_readlane((int)(unsigned)ee.x, e);
                unsigned bhi = (unsigned)__builtin_amdgcn_readlane((int)(unsigned)(ee.x >> 32), e);
                u64 bits = ((u64)bhi << 32) | (u64)blo;
                int es = (int)(ew >> 6), eo = (int)(ew & 63u);
                u64 add = (lane == eo) ? bits : 0ull;
                if (es == 0) rem[0] |= add; else if (es == 1) rem[1] |= add; else rem[2] |= add;
            }
            if (c > (unsigned)EC) {               // rare overflow entries from global
                unsigned cm = min(c, (unsigned)CAP);
                for (unsigned e = EC; e < cm; ++e) {
                    ulonglong2 g = ent_g[(size_t)r * CAP + e];
                    int es = (int)(g.y >> 6), eo = (int)(g.y & 63u);
                    u64 add = (lane == eo) ? g.x : 0ull;
                    if (es == 0) rem[0] |= add; else if (es == 1) rem[1] |= add; else rem[2] |= add;
                }
            }
        }
    }
    // tail: rows beyond LDS preload (rare) straight from global
    for (int k = kcap; k < n_nz; ++k) {
        int r = list[k];
        int w = r >> 6, slot = w >> 6, owner = w & 63, b = r & 63;
        u64 remw = (slot == 0) ? rem[0] : ((slot == 1) ? rem[1] : rem[2]);
        unsigned sel = (b < 32) ? (unsigned)remw : (unsigned)(remw >> 32);
        unsigned word = (unsigned)__builtin_amdgcn_readlane((int)sel, owner);
        if (!((word >> (b & 31)) & 1u)) {
            unsigned c = min(cnt_g[r], (unsigned)CAP);
            for (unsigned e = 0; e < c; ++e) {
                ulonglong2 g = ent_g[(size_t)r * CAP + e];
                int es = (int)(g.y >> 6), eo = (int)(g.y & 63u);
                u64 add = (lane == eo) ? g.x : 0ull;
                if (es == 0) rem[0] |= add; else if (es == 1) rem[1] |= add; else rem[2] |= add;
            }
        }
    }

    #pragma unroll
    for (int s = 0; s < 3; ++s) {
        int w = s * 64 + lane;
        if (w < MASK_WORDS) keep_words[w] = vw[s] & ~rem[s];
    }
}

// ---------------- K6: write outputs ----------------
__global__ void output_kernel(const float* __restrict__ s_sig, const float* __restrict__ s_box,
                              const float* __restrict__ s_kps,
                              const u64* __restrict__ keep_words,
                              float* __restrict__ out) {
    int r = blockIdx.x * blockDim.x + threadIdx.x;
    if (r >= N_TOT) return;
    float m = ((keep_words[r >> 6] >> (r & 63)) & 1ull) ? 1.0f : 0.0f;
    float* ob = out;                   // 8400*4
    float* os = out + 33600;           // 8400
    float* okp = out + 42000;          // 8400*10
    float* om = out + 126000;          // 8400
    #pragma unroll
    for (int c = 0; c < 4; ++c)  ob[r*4+c] = s_box[r*4+c] * m;
    os[r] = s_sig[r] * m;
    #pragma unroll
    for (int c = 0; c < 10; ++c) okp[r*10+c] = s_kps[r*10+c] * m;
    om[r] = m;
}

extern "C" void kernel_launch(void* const* d_in, const int* in_sizes, int n_in,
                              void* d_out, int out_size, void* d_ws, size_t ws_size,
                              hipStream_t stream) {
    const float *score0, *bbox0, *kps0, *score1, *bbox1, *kps1, *score2, *bbox2, *kps2;
    if (in_sizes[1] == 25600) {
        score0 = (const float*)d_in[0]; bbox0 = (const float*)d_in[1]; kps0 = (const float*)d_in[2];
        score1 = (const float*)d_in[3]; bbox1 = (const float*)d_in[4]; kps1 = (const float*)d_in[5];
        score2 = (const float*)d_in[6]; bbox2 = (const float*)d_in[7]; kps2 = (const float*)d_in[8];
    } else {
        score0 = (const float*)d_in[0]; score1 = (const float*)d_in[1]; score2 = (const float*)d_in[2];
        bbox0  = (const float*)d_in[3]; bbox1  = (const float*)d_in[4]; bbox2  = (const float*)d_in[5];
        kps0   = (const float*)d_in[6]; kps1   = (const float*)d_in[7]; kps2   = (const float*)d_in[8];
    }

    char* ws = (char*)d_ws;
    float* logit   = (float*)(ws + 0);
    float* sig     = (float*)(ws + 33600);
    float* box     = (float*)(ws + 67200);
    float* kps     = (float*)(ws + 201600);
    int*   rank    = (int*)  (ws + 537600);
    float* s_logit = (float*)(ws + 571200);
    float* s_sig   = (float*)(ws + 604800);
    float* s_box   = (float*)(ws + 638400);
    float* s_kps   = (float*)(ws + 772800);          // ends 1108800
    u64*   keep_words = (u64*)(ws + 1108800);        // 1056 B
    u64*   validw     = (u64*)(ws + 1110144);        // 1056 B
    u64*   rowflag    = (u64*)(ws + 1111296);        // 1056 B
    unsigned int* cnt = (unsigned int*)(ws + 1112448);   // 33600 B
    ulonglong2*   ent = (ulonglong2*)(ws + 1146368);     // 8400*32*16 = 4.3 MB

    float* out = (float*)d_out;

    decode_kernel<<<(N_TOT + 255) / 256, 256, 0, stream>>>(
        score0, bbox0, kps0, score1, bbox1, kps1, score2, bbox2, kps2,
        logit, sig, box, kps);
    rank_kernel<<<33, 256, 0, stream>>>(logit, rank);
    scatter_kernel<<<33, 256, 0, stream>>>(rank, logit, sig, box, kps,
                                           s_logit, s_sig, s_box, s_kps);
    prep_kernel<<<MASK_WORDS, 64, 0, stream>>>(s_logit, validw, rowflag, cnt);
    pairs_kernel<<<dim3(MASK_WORDS, MASK_WORDS), 64, 0, stream>>>(s_logit, s_box, cnt, ent, rowflag);
    nms_kernel<<<1, 64, 0, stream>>>(rowflag, validw, cnt, ent, keep_words);
    output_kernel<<<33, 256, 0, stream>>>(s_sig, s_box, s_kps, keep_words, out);
}

// Round 3
// 111.363 us; speedup vs baseline: 20.1268x; 2.8853x over previous
//
#include <hip/hip_runtime.h>
#include <math.h>

#define N_TOT 8400
#define MASK_WORDS 132   // ceil(8400/64)
#define CAP 32           // max (word,bits) entries per row
#define LDSN 1024        // rows preloaded into LDS in nms
#define EC 2             // entries per row preloaded into LDS
#define RT 33            // rank tiles: ceil(8400/256)

typedef unsigned long long u64;

// monotone-increasing float->u32 mapping
__device__ __forceinline__ unsigned mono_u32(float f) {
    unsigned u = __float_as_uint(f);
    return (u & 0x80000000u) ? ~u : (u | 0x80000000u);
}

// ---------------- K1: decode all 3 scales + build sort keys + zero-init state ----------------
__global__ void decode_kernel(const float* __restrict__ score0, const float* __restrict__ bbox0, const float* __restrict__ kps0,
                              const float* __restrict__ score1, const float* __restrict__ bbox1, const float* __restrict__ kps1,
                              const float* __restrict__ score2, const float* __restrict__ bbox2, const float* __restrict__ kps2,
                              float* __restrict__ logit, float* __restrict__ sig,
                              float* __restrict__ box, float* __restrict__ kps,
                              u64* __restrict__ key, int* __restrict__ rank,
                              unsigned int* __restrict__ cnt,
                              u64* __restrict__ validw, u64* __restrict__ rowflag) {
    int i = blockIdx.x * blockDim.x + threadIdx.x;
    if (i >= N_TOT) return;
    if (i < MASK_WORDS) { validw[i] = 0ull; rowflag[i] = 0ull; }
    rank[i] = 0;
    cnt[i] = 0u;
    const float *sc, *bb, *kp;
    int m, F; float s;
    if (i < 6400)      { sc = score0; bb = bbox0; kp = kps0; m = i;        F = 80; s = 8.f;  }
    else if (i < 8000) { sc = score1; bb = bbox1; kp = kps1; m = i - 6400; F = 40; s = 16.f; }
    else               { sc = score2; bb = bbox2; kp = kps2; m = i - 8000; F = 20; s = 32.f; }
    float px = (float)(m % F) * s;
    float py = (float)(m / F) * s;
    float lg = sc[m];
    logit[i] = lg;
    sig[i] = 1.0f / (1.0f + expf(-lg));
    // descending-logit order with ascending-index tie-break, as one u64 key (ascending)
    key[i] = ((u64)(~mono_u32(lg)) << 14) | (u64)i;
    float d0 = bb[m*4+0]*s, d1 = bb[m*4+1]*s, d2 = bb[m*4+2]*s, d3 = bb[m*4+3]*s;
    box[i*4+0] = px - d0;
    box[i*4+1] = py - d1;
    box[i*4+2] = px + d2;
    box[i*4+3] = py + d3;
    #pragma unroll
    for (int c = 0; c < 5; ++c) {
        kps[i*10 + 2*c]   = px + kp[m*10 + 2*c]   * s;
        kps[i*10 + 2*c+1] = py + kp[m*10 + 2*c+1] * s;
    }
}

// ---------------- K2: tiled rank = #{j : key[j] < key[i]} ----------------
__global__ __launch_bounds__(256) void rank_kernel(const u64* __restrict__ key, int* __restrict__ rank) {
    __shared__ u64 tile[256];
    int i = blockIdx.x * 256 + threadIdx.x;
    int t0 = blockIdx.y * 256;
    u64 ki = (i < N_TOT) ? key[i] : 0ull;
    int j = t0 + threadIdx.x;
    tile[threadIdx.x] = (j < N_TOT) ? key[j] : ~0ull;   // OOB sorts last (never < ki)
    __syncthreads();
    if (i >= N_TOT) return;
    int rk = 0;
    #pragma unroll 8
    for (int k = 0; k < 256; ++k) {
        rk += (tile[k] < ki) ? 1 : 0;
    }
    if (rk) atomicAdd(&rank[i], rk);
}

// ---------------- K3: scatter into sorted order + set valid bits ----------------
__global__ void scatter_kernel(const int* __restrict__ rank,
                               const float* __restrict__ logit, const float* __restrict__ sig,
                               const float* __restrict__ box, const float* __restrict__ kps,
                               float* __restrict__ s_logit, float* __restrict__ s_sig,
                               float* __restrict__ s_box, float* __restrict__ s_kps,
                               u64* __restrict__ validw) {
    int i = blockIdx.x * blockDim.x + threadIdx.x;
    if (i >= N_TOT) return;
    int r = rank[i];
    float lg = logit[i];
    s_logit[r] = lg;
    s_sig[r] = sig[i];
    #pragma unroll
    for (int c = 0; c < 4; ++c)  s_box[r*4+c] = box[i*4+c];
    #pragma unroll
    for (int c = 0; c < 10; ++c) s_kps[r*10+c] = kps[i*10+c];
    if (lg > 0.f) atomicOr(&validw[r >> 6], 1ull << (r & 63));
}

// ---------------- K4: sparse successor-overlap pairs ----------------
__global__ __launch_bounds__(64) void pairs_kernel(const float* __restrict__ s_logit,
                                                   const float* __restrict__ s_box,
                                                   unsigned int* __restrict__ cnt,
                                                   ulonglong2* __restrict__ ent,
                                                   u64* __restrict__ rowflag) {
    int cw = blockIdx.x;   // column word 0..131
    int rb = blockIdx.y;   // row block 0..131
    if (cw < rb) return;   // all j <= r in these blocks
    int tid = threadIdx.x;

    __shared__ float cbx1[64], cby1[64], cbx2[64], cby2[64], carea[64];
    int j0 = cw * 64;
    int j = j0 + tid;
    float x1 = 0.f, y1 = 0.f, x2 = 0.f, y2 = 0.f, lgj = -1.f;
    if (j < N_TOT) {
        x1 = s_box[j*4+0]; y1 = s_box[j*4+1]; x2 = s_box[j*4+2]; y2 = s_box[j*4+3];
        lgj = s_logit[j];
    }
    cbx1[tid] = x1; cby1[tid] = y1; cbx2[tid] = x2; cby2[tid] = y2;
    carea[tid] = (x2 - x1) * (y2 - y1);
    u64 cvalid = __ballot(j < N_TOT && lgj > 0.f);
    __syncthreads();
    if (cvalid == 0ull) return;     // no valid columns (sorted => ranks >= V)

    int r = rb * 64 + tid;
    if (r >= N_TOT) return;
    float lgr = s_logit[r];
    if (lgr <= 0.f) return;

    float rx1 = s_box[r*4+0], ry1 = s_box[r*4+1], rx2 = s_box[r*4+2], ry2 = s_box[r*4+3];
    float rarea = (rx2 - rx1) * (ry2 - ry1);
    u64 bits = 0ull;
    for (int k = 0; k < 64; ++k) {
        int jj = j0 + k;
        if (jj <= r) continue;
        if (!((cvalid >> k) & 1ull)) continue;
        float ltx = fmaxf(rx1, cbx1[k]);
        float lty = fmaxf(ry1, cby1[k]);
        float rbx = fminf(rx2, cbx2[k]);
        float rby = fminf(ry2, cby2[k]);
        float w = fmaxf(rbx - ltx, 0.f);
        float h = fmaxf(rby - lty, 0.f);
        float inter = w * h;
        float iou = inter / (rarea + carea[k] - inter + 1e-9f);
        if (iou > 0.4f) bits |= (1ull << k);
    }
    if (bits) {
        unsigned idx = atomicAdd(&cnt[r], 1u);
        if (idx < CAP) {
            ulonglong2 e; e.x = bits; e.y = (u64)cw;
            ent[(size_t)r * CAP + idx] = e;
        }
        atomicOr(&rowflag[r >> 6], 1ull << (r & 63));
    }
}

// ---------------- K5: serial greedy resolve over SPARSE rows (one wave) ----------------
__global__ __launch_bounds__(64) void nms_kernel(const u64* __restrict__ rowflag_g,
                                                 const u64* __restrict__ validw_g,
                                                 const unsigned int* __restrict__ cnt_g,
                                                 const ulonglong2* __restrict__ ent_g,
                                                 u64* __restrict__ keep_words) {
    __shared__ unsigned short list[8448];   // nonzero rows, sorted ascending
    __shared__ unsigned int   lcnt[LDSN];
    __shared__ ulonglong2     lent[LDSN * EC];
    int lane = threadIdx.x;

    u64 rf[3], vw[3];
    #pragma unroll
    for (int s = 0; s < 3; ++s) {
        int w = s * 64 + lane;
        rf[s] = (w < MASK_WORDS) ? rowflag_g[w] : 0ull;
        vw[s] = (w < MASK_WORDS) ? validw_g[w] : 0ull;
    }

    // Build sorted nonzero-row list via wave prefix sums (3 slot phases).
    int base = 0;
    #pragma unroll
    for (int s = 0; s < 3; ++s) {
        int c = (int)__popcll(rf[s]);
        int x = c;
        #pragma unroll
        for (int o = 1; o < 64; o <<= 1) { int y = __shfl_up(x, o); if (lane >= o) x += y; }
        int excl = x - c;
        int total = __shfl(x, 63);
        int off = base + excl;
        u64 t = rf[s];
        int wbase = (s * 64 + lane) << 6;
        while (t) {
            int b = __builtin_ctzll(t); t &= t - 1;
            list[off++] = (unsigned short)(wbase | b);
        }
        base += total;
    }
    int n_nz = base;
    __syncthreads();

    // Preload cnt + first EC entries per listed row into LDS (parallel).
    int kcap = min(n_nz, LDSN);
    for (int k = lane; k < kcap; k += 64) {
        int r = list[k];
        unsigned c = cnt_g[r];
        lcnt[k] = c;
        unsigned cc = min(c, (unsigned)EC);
        for (unsigned e = 0; e < cc; ++e) lent[k * EC + e] = ent_g[(size_t)r * CAP + e];
    }
    __syncthreads();

    u64 rem[3] = {0ull, 0ull, 0ull};

    // depth-2 pipelined serial loop over LDS-resident rows
    int r_n = 0; unsigned c_n = 0; ulonglong2 e_n; e_n.x = 0; e_n.y = 0;
    if (kcap > 0) {
        r_n = list[0];
        c_n = lcnt[0];
        if (lane < EC) e_n = lent[lane];
    }
    for (int k = 0; k < kcap; ++k) {
        int r = r_n; unsigned c = c_n; ulonglong2 ee = e_n;
        int kn = k + 1;
        if (kn < kcap) {
            r_n = list[kn];
            c_n = lcnt[kn];
            if (lane < EC) e_n = lent[kn * EC + lane];
        }
        int w = r >> 6, slot = w >> 6, owner = w & 63, b = r & 63;
        u64 remw = (slot == 0) ? rem[0] : ((slot == 1) ? rem[1] : rem[2]);
        unsigned sel = (b < 32) ? (unsigned)remw : (unsigned)(remw >> 32);
        unsigned word = (unsigned)__builtin_amdgcn_readlane((int)sel, owner);
        if (!((word >> (b & 31)) & 1u)) {
            int cc = (int)min(c, (unsigned)EC);
            for (int e = 0; e < cc; ++e) {
                unsigned ew  = (unsigned)__builtin_amdgcn_readlane((int)(unsigned)ee.y, e);
                unsigned blo = (unsigned)__builtin_amdgcn_readlane((int)(unsigned)ee.x, e);
                unsigned bhi = (unsigned)__builtin_amdgcn_readlane((int)(unsigned)(ee.x >> 32), e);
                u64 bits = ((u64)bhi << 32) | (u64)blo;
                int es = (int)(ew >> 6), eo = (int)(ew & 63u);
                u64 add = (lane == eo) ? bits : 0ull;
                if (es == 0) rem[0] |= add; else if (es == 1) rem[1] |= add; else rem[2] |= add;
            }
            if (c > (unsigned)EC) {               // rare overflow entries from global
                unsigned cm = min(c, (unsigned)CAP);
                for (unsigned e = EC; e < cm; ++e) {
                    ulonglong2 g = ent_g[(size_t)r * CAP + e];
                    int es = (int)(g.y >> 6), eo = (int)(g.y & 63u);
                    u64 add = (lane == eo) ? g.x : 0ull;
                    if (es == 0) rem[0] |= add; else if (es == 1) rem[1] |= add; else rem[2] |= add;
                }
            }
        }
    }
    // tail: rows beyond LDS preload (rare) straight from global
    for (int k = kcap; k < n_nz; ++k) {
        int r = list[k];
        int w = r >> 6, slot = w >> 6, owner = w & 63, b = r & 63;
        u64 remw = (slot == 0) ? rem[0] : ((slot == 1) ? rem[1] : rem[2]);
        unsigned sel = (b < 32) ? (unsigned)remw : (unsigned)(remw >> 32);
        unsigned word = (unsigned)__builtin_amdgcn_readlane((int)sel, owner);
        if (!((word >> (b & 31)) & 1u)) {
            unsigned c = min(cnt_g[r], (unsigned)CAP);
            for (unsigned e = 0; e < c; ++e) {
                ulonglong2 g = ent_g[(size_t)r * CAP + e];
                int es = (int)(g.y >> 6), eo = (int)(g.y & 63u);
                u64 add = (lane == eo) ? g.x : 0ull;
                if (es == 0) rem[0] |= add; else if (es == 1) rem[1] |= add; else rem[2] |= add;
            }
        }
    }

    #pragma unroll
    for (int s = 0; s < 3; ++s) {
        int w = s * 64 + lane;
        if (w < MASK_WORDS) keep_words[w] = vw[s] & ~rem[s];
    }
}

// ---------------- K6: write outputs ----------------
__global__ void output_kernel(const float* __restrict__ s_sig, const float* __restrict__ s_box,
                              const float* __restrict__ s_kps,
                              const u64* __restrict__ keep_words,
                              float* __restrict__ out) {
    int r = blockIdx.x * blockDim.x + threadIdx.x;
    if (r >= N_TOT) return;
    float m = ((keep_words[r >> 6] >> (r & 63)) & 1ull) ? 1.0f : 0.0f;
    float* ob = out;                   // 8400*4
    float* os = out + 33600;           // 8400
    float* okp = out + 42000;          // 8400*10
    float* om = out + 126000;          // 8400
    #pragma unroll
    for (int c = 0; c < 4; ++c)  ob[r*4+c] = s_box[r*4+c] * m;
    os[r] = s_sig[r] * m;
    #pragma unroll
    for (int c = 0; c < 10; ++c) okp[r*10+c] = s_kps[r*10+c] * m;
    om[r] = m;
}

extern "C" void kernel_launch(void* const* d_in, const int* in_sizes, int n_in,
                              void* d_out, int out_size, void* d_ws, size_t ws_size,
                              hipStream_t stream) {
    const float *score0, *bbox0, *kps0, *score1, *bbox1, *kps1, *score2, *bbox2, *kps2;
    if (in_sizes[1] == 25600) {
        score0 = (const float*)d_in[0]; bbox0 = (const float*)d_in[1]; kps0 = (const float*)d_in[2];
        score1 = (const float*)d_in[3]; bbox1 = (const float*)d_in[4]; kps1 = (const float*)d_in[5];
        score2 = (const float*)d_in[6]; bbox2 = (const float*)d_in[7]; kps2 = (const float*)d_in[8];
    } else {
        score0 = (const float*)d_in[0]; score1 = (const float*)d_in[1]; score2 = (const float*)d_in[2];
        bbox0  = (const float*)d_in[3]; bbox1  = (const float*)d_in[4]; bbox2  = (const float*)d_in[5];
        kps0   = (const float*)d_in[6]; kps1   = (const float*)d_in[7]; kps2   = (const float*)d_in[8];
    }

    char* ws = (char*)d_ws;
    float* logit   = (float*)(ws + 0);
    float* sig     = (float*)(ws + 33600);
    float* box     = (float*)(ws + 67200);
    float* kps     = (float*)(ws + 201600);
    int*   rank    = (int*)  (ws + 537600);
    float* s_logit = (float*)(ws + 571200);
    float* s_sig   = (float*)(ws + 604800);
    float* s_box   = (float*)(ws + 638400);
    float* s_kps   = (float*)(ws + 772800);          // ends 1108800
    u64*   keep_words = (u64*)(ws + 1108800);        // 1056 B
    u64*   validw     = (u64*)(ws + 1110144);        // 1056 B
    u64*   rowflag    = (u64*)(ws + 1111296);        // 1056 B
    unsigned int* cnt = (unsigned int*)(ws + 1112448);   // 33600 B
    u64*   key        = (u64*)(ws + 1146368);            // 67200 B
    ulonglong2*   ent = (ulonglong2*)(ws + 1213568);     // 8400*32*16 = 4.3 MB

    float* out = (float*)d_out;

    decode_kernel<<<(N_TOT + 255) / 256, 256, 0, stream>>>(
        score0, bbox0, kps0, score1, bbox1, kps1, score2, bbox2, kps2,
        logit, sig, box, kps, key, rank, cnt, validw, rowflag);
    rank_kernel<<<dim3(RT, RT), 256, 0, stream>>>(key, rank);
    scatter_kernel<<<33, 256, 0, stream>>>(rank, logit, sig, box, kps,
                                           s_logit, s_sig, s_box, s_kps, validw);
    pairs_kernel<<<dim3(MASK_WORDS, MASK_WORDS), 64, 0, stream>>>(s_logit, s_box, cnt, ent, rowflag);
    nms_kernel<<<1, 64, 0, stream>>>(rowflag, validw, cnt, ent, keep_words);
    output_kernel<<<33, 256, 0, stream>>>(s_sig, s_box, s_kps, keep_words, out);
}

// Round 4
// 107.910 us; speedup vs baseline: 20.7707x; 1.0320x over previous
//
#include <hip/hip_runtime.h>
#include <math.h>

#define N_TOT 8400
#define MASK_WORDS 132   // ceil(8400/64)
#define CAP 32           // max (word,bits) entries per row
#define RT 33            // rank tiles: ceil(8400/256)

typedef unsigned long long u64;

// monotone-increasing float->u32 mapping
__device__ __forceinline__ unsigned mono_u32(float f) {
    unsigned u = __float_as_uint(f);
    return (u & 0x80000000u) ? ~u : (u | 0x80000000u);
}

// ---------------- K1: decode all 3 scales + build sort keys + zero-init state ----------------
__global__ void decode_kernel(const float* __restrict__ score0, const float* __restrict__ bbox0, const float* __restrict__ kps0,
                              const float* __restrict__ score1, const float* __restrict__ bbox1, const float* __restrict__ kps1,
                              const float* __restrict__ score2, const float* __restrict__ bbox2, const float* __restrict__ kps2,
                              float* __restrict__ logit, float* __restrict__ sig,
                              float* __restrict__ box, float* __restrict__ kps,
                              u64* __restrict__ key, int* __restrict__ rank,
                              unsigned int* __restrict__ cnt,
                              u64* __restrict__ validw, u64* __restrict__ rowflag) {
    int i = blockIdx.x * blockDim.x + threadIdx.x;
    if (i >= N_TOT) return;
    if (i < MASK_WORDS) { validw[i] = 0ull; rowflag[i] = 0ull; }
    rank[i] = 0;
    cnt[i] = 0u;
    const float *sc, *bb, *kp;
    int m, F; float s;
    if (i < 6400)      { sc = score0; bb = bbox0; kp = kps0; m = i;        F = 80; s = 8.f;  }
    else if (i < 8000) { sc = score1; bb = bbox1; kp = kps1; m = i - 6400; F = 40; s = 16.f; }
    else               { sc = score2; bb = bbox2; kp = kps2; m = i - 8000; F = 20; s = 32.f; }
    float px = (float)(m % F) * s;
    float py = (float)(m / F) * s;
    float lg = sc[m];
    logit[i] = lg;
    sig[i] = 1.0f / (1.0f + expf(-lg));
    // descending-logit order with ascending-index tie-break, as one u64 key (ascending)
    key[i] = ((u64)(~mono_u32(lg)) << 14) | (u64)i;
    float d0 = bb[m*4+0]*s, d1 = bb[m*4+1]*s, d2 = bb[m*4+2]*s, d3 = bb[m*4+3]*s;
    box[i*4+0] = px - d0;
    box[i*4+1] = py - d1;
    box[i*4+2] = px + d2;
    box[i*4+3] = py + d3;
    #pragma unroll
    for (int c = 0; c < 5; ++c) {
        kps[i*10 + 2*c]   = px + kp[m*10 + 2*c]   * s;
        kps[i*10 + 2*c+1] = py + kp[m*10 + 2*c+1] * s;
    }
}

// ---------------- K2: tiled rank = #{j : key[j] < key[i]} ----------------
__global__ __launch_bounds__(256) void rank_kernel(const u64* __restrict__ key, int* __restrict__ rank) {
    __shared__ u64 tile[256];
    int i = blockIdx.x * 256 + threadIdx.x;
    int t0 = blockIdx.y * 256;
    u64 ki = (i < N_TOT) ? key[i] : 0ull;
    int j = t0 + threadIdx.x;
    tile[threadIdx.x] = (j < N_TOT) ? key[j] : ~0ull;   // OOB sorts last (never < ki)
    __syncthreads();
    if (i >= N_TOT) return;
    int rk = 0;
    #pragma unroll 8
    for (int k = 0; k < 256; ++k) {
        rk += (tile[k] < ki) ? 1 : 0;
    }
    if (rk) atomicAdd(&rank[i], rk);
}

// ---------------- K3: scatter into sorted order + set valid bits ----------------
__global__ void scatter_kernel(const int* __restrict__ rank,
                               const float* __restrict__ logit, const float* __restrict__ sig,
                               const float* __restrict__ box, const float* __restrict__ kps,
                               float* __restrict__ s_logit, float* __restrict__ s_sig,
                               float* __restrict__ s_box, float* __restrict__ s_kps,
                               u64* __restrict__ validw) {
    int i = blockIdx.x * blockDim.x + threadIdx.x;
    if (i >= N_TOT) return;
    int r = rank[i];
    float lg = logit[i];
    s_logit[r] = lg;
    s_sig[r] = sig[i];
    #pragma unroll
    for (int c = 0; c < 4; ++c)  s_box[r*4+c] = box[i*4+c];
    #pragma unroll
    for (int c = 0; c < 10; ++c) s_kps[r*10+c] = kps[i*10+c];
    if (lg > 0.f) atomicOr(&validw[r >> 6], 1ull << (r & 63));
}

// ---------------- K4: sparse successor-overlap pairs (branch-free inner loop) ----------------
__global__ __launch_bounds__(64) void pairs_kernel(const float* __restrict__ s_logit,
                                                   const float* __restrict__ s_box,
                                                   unsigned int* __restrict__ cnt,
                                                   ulonglong2* __restrict__ ent,
                                                   u64* __restrict__ rowflag) {
    int cw = blockIdx.x;   // column word 0..131
    int rb = blockIdx.y;   // row block 0..131
    if (cw < rb) return;   // all j <= r in these blocks
    int tid = threadIdx.x;

    __shared__ float4 cbox[64];
    __shared__ float  carea[64];
    int j0 = cw * 64;
    int j = j0 + tid;
    float4 cb = make_float4(0.f, 0.f, 0.f, 0.f);
    float lgj = -1.f;
    if (j < N_TOT) {
        cb = ((const float4*)s_box)[j];
        lgj = s_logit[j];
    }
    cbox[tid] = cb;
    carea[tid] = (cb.z - cb.x) * (cb.w - cb.y);
    u64 cvalid = __ballot(j < N_TOT && lgj > 0.f);
    __syncthreads();
    if (cvalid == 0ull) return;     // no valid columns (sorted => ranks >= V)

    int r = rb * 64 + tid;
    float lgr = (r < N_TOT) ? s_logit[r] : -1.f;
    if (__ballot(lgr > 0.f) == 0ull) return;   // whole wave of invalid rows

    u64 bits = 0ull;
    if (lgr > 0.f) {
        float4 rb4 = ((const float4*)s_box)[r];
        float rarea = (rb4.z - rb4.x) * (rb4.w - rb4.y);
        #pragma unroll 4
        for (int k = 0; k < 64; ++k) {
            float4 c4 = cbox[k];
            float ltx = fmaxf(rb4.x, c4.x);
            float lty = fmaxf(rb4.y, c4.y);
            float rbx = fminf(rb4.z, c4.z);
            float rby = fminf(rb4.w, c4.w);
            float w = fmaxf(rbx - ltx, 0.f);
            float h = fmaxf(rby - lty, 0.f);
            float inter = w * h;
            float iou = inter / (rarea + carea[k] - inter + 1e-9f);
            bits |= (iou > 0.4f) ? (1ull << k) : 0ull;
        }
        u64 m = cvalid;                                  // only valid columns
        if (cw == rb) m &= (tid == 63) ? 0ull : (~0ull << (tid + 1));  // only strict successors
        bits &= m;
    }
    if (bits) {
        unsigned idx = atomicAdd(&cnt[r], 1u);
        if (idx < CAP) {
            ulonglong2 e; e.x = bits; e.y = (u64)cw;
            ent[(size_t)r * CAP + idx] = e;
        }
        atomicOr(&rowflag[r >> 6], 1ull << (r & 63));
    }
}

// ---------------- K5: serial greedy resolve, register-resident chunks (one wave) ----------------
// Rows with >=1 outgoing edge processed in chunks of 32. Per chunk, lane layout:
//   lane i    (i<32): row id, cnt, entry0 of chunk-row i
//   lane 32+i (i<32): entry1 of chunk-row i
// Serial loop uses only v_readlane + scalar ops -- no LDS/global on critical path.
__global__ __launch_bounds__(64) void nms_kernel(const u64* __restrict__ rowflag_g,
                                                 const u64* __restrict__ validw_g,
                                                 const unsigned int* __restrict__ cnt_g,
                                                 const ulonglong2* __restrict__ ent_g,
                                                 u64* __restrict__ keep_words) {
    __shared__ unsigned short list[8448];   // nonzero rows, sorted ascending
    int lane = threadIdx.x;

    u64 rf[3], vw[3];
    #pragma unroll
    for (int s = 0; s < 3; ++s) {
        int w = s * 64 + lane;
        rf[s] = (w < MASK_WORDS) ? rowflag_g[w] : 0ull;
        vw[s] = (w < MASK_WORDS) ? validw_g[w] : 0ull;
    }

    // Build sorted nonzero-row list via wave prefix sums (3 slot phases).
    int base = 0;
    #pragma unroll
    for (int s = 0; s < 3; ++s) {
        int c = (int)__popcll(rf[s]);
        int x = c;
        #pragma unroll
        for (int o = 1; o < 64; o <<= 1) { int y = __shfl_up(x, o); if (lane >= o) x += y; }
        int excl = x - c;
        int total = __shfl(x, 63);
        int off = base + excl;
        u64 t = rf[s];
        int wbase = (s * 64 + lane) << 6;
        while (t) {
            int b = __builtin_ctzll(t); t &= t - 1;
            list[off++] = (unsigned short)(wbase | b);
        }
        base += total;
    }
    int n_nz = base;
    __syncthreads();

    u64 rem0 = 0ull, rem1 = 0ull, rem2 = 0ull;

    if (n_nz > 0) {
        int half = lane >> 5;      // which entry this lane carries
        int sub  = lane & 31;      // chunk-row index

        // load chunk 0
        int idx0 = min(sub, n_nz - 1);
        int rowCur = list[idx0];
        unsigned cntCur = cnt_g[rowCur];
        ulonglong2 entCur = ent_g[(size_t)rowCur * CAP + half];

        for (int k0 = 0; k0 < n_nz; k0 += 32) {
            // prefetch next chunk (globals fly during current chunk's serial body)
            int nb = k0 + 32;
            int rowNxt = 0; unsigned cntNxt = 0u;
            ulonglong2 entNxt; entNxt.x = 0ull; entNxt.y = 0ull;
            if (nb < n_nz) {
                int idx = min(nb + sub, n_nz - 1);
                rowNxt = list[idx];
                cntNxt = cnt_g[rowNxt];
                entNxt = ent_g[(size_t)rowNxt * CAP + half];
            }

            int lim = min(32, n_nz - k0);
            for (int i = 0; i < lim; ++i) {
                int r = __builtin_amdgcn_readlane(rowCur, i);          // SGPR
                int w = r >> 6, slot = w >> 6, owner = w & 63, b = r & 63;
                u64 rw = (slot == 0) ? rem0 : ((slot == 1) ? rem1 : rem2);
                unsigned halfw = (b < 32) ? (unsigned)rw : (unsigned)(rw >> 32);
                unsigned word = (unsigned)__builtin_amdgcn_readlane((int)halfw, owner);
                if (!((word >> (b & 31)) & 1u)) {                      // row kept -> apply edges
                    unsigned c = (unsigned)__builtin_amdgcn_readlane((int)cntCur, i);
                    int ec = (int)min(c, 2u);
                    for (int e = 0; e < ec; ++e) {
                        int src = e * 32 + i;
                        unsigned ey  = (unsigned)__builtin_amdgcn_readlane((int)(unsigned)entCur.y, src);
                        unsigned blo = (unsigned)__builtin_amdgcn_readlane((int)(unsigned)entCur.x, src);
                        unsigned bhi = (unsigned)__builtin_amdgcn_readlane((int)(unsigned)(entCur.x >> 32), src);
                        u64 bits = ((u64)bhi << 32) | (u64)blo;
                        int es = (int)(ey >> 6), eo = (int)(ey & 63u);
                        u64 add = (lane == eo) ? bits : 0ull;
                        if (es == 0) rem0 |= add; else if (es == 1) rem1 |= add; else rem2 |= add;
                    }
                    if (c > 2u) {                                      // rare overflow entries
                        unsigned cm = min(c, (unsigned)CAP);
                        for (unsigned e = 2; e < cm; ++e) {
                            ulonglong2 g = ent_g[(size_t)r * CAP + e];
                            int es = (int)(g.y >> 6), eo = (int)(g.y & 63u);
                            u64 add = (lane == eo) ? g.x : 0ull;
                            if (es == 0) rem0 |= add; else if (es == 1) rem1 |= add; else rem2 |= add;
                        }
                    }
                }
            }
            rowCur = rowNxt; cntCur = cntNxt; entCur = entNxt;
        }
    }

    u64 rem[3] = {rem0, rem1, rem2};
    #pragma unroll
    for (int s = 0; s < 3; ++s) {
        int w = s * 64 + lane;
        if (w < MASK_WORDS) keep_words[w] = vw[s] & ~rem[s];
    }
}

// ---------------- K6: write outputs ----------------
__global__ void output_kernel(const float* __restrict__ s_sig, const float* __restrict__ s_box,
                              const float* __restrict__ s_kps,
                              const u64* __restrict__ keep_words,
                              float* __restrict__ out) {
    int r = blockIdx.x * blockDim.x + threadIdx.x;
    if (r >= N_TOT) return;
    float m = ((keep_words[r >> 6] >> (r & 63)) & 1ull) ? 1.0f : 0.0f;
    float* ob = out;                   // 8400*4
    float* os = out + 33600;           // 8400
    float* okp = out + 42000;          // 8400*10
    float* om = out + 126000;          // 8400
    #pragma unroll
    for (int c = 0; c < 4; ++c)  ob[r*4+c] = s_box[r*4+c] * m;
    os[r] = s_sig[r] * m;
    #pragma unroll
    for (int c = 0; c < 10; ++c) okp[r*10+c] = s_kps[r*10+c] * m;
    om[r] = m;
}

extern "C" void kernel_launch(void* const* d_in, const int* in_sizes, int n_in,
                              void* d_out, int out_size, void* d_ws, size_t ws_size,
                              hipStream_t stream) {
    const float *score0, *bbox0, *kps0, *score1, *bbox1, *kps1, *score2, *bbox2, *kps2;
    if (in_sizes[1] == 25600) {
        score0 = (const float*)d_in[0]; bbox0 = (const float*)d_in[1]; kps0 = (const float*)d_in[2];
        score1 = (const float*)d_in[3]; bbox1 = (const float*)d_in[4]; kps1 = (const float*)d_in[5];
        score2 = (const float*)d_in[6]; bbox2 = (const float*)d_in[7]; kps2 = (const float*)d_in[8];
    } else {
        score0 = (const float*)d_in[0]; score1 = (const float*)d_in[1]; score2 = (const float*)d_in[2];
        bbox0  = (const float*)d_in[3]; bbox1  = (const float*)d_in[4]; bbox2  = (const float*)d_in[5];
        kps0   = (const float*)d_in[6]; kps1   = (const float*)d_in[7]; kps2   = (const float*)d_in[8];
    }

    char* ws = (char*)d_ws;
    float* logit   = (float*)(ws + 0);
    float* sig     = (float*)(ws + 33600);
    float* box     = (float*)(ws + 67200);
    float* kps     = (float*)(ws + 201600);
    int*   rank    = (int*)  (ws + 537600);
    float* s_logit = (float*)(ws + 571200);
    float* s_sig   = (float*)(ws + 604800);
    float* s_box   = (float*)(ws + 638400);          // 16B-aligned (float4 loads)
    float* s_kps   = (float*)(ws + 772800);          // ends 1108800
    u64*   keep_words = (u64*)(ws + 1108800);        // 1056 B
    u64*   validw     = (u64*)(ws + 1110144);        // 1056 B
    u64*   rowflag    = (u64*)(ws + 1111296);        // 1056 B
    unsigned int* cnt = (unsigned int*)(ws + 1112448);   // 33600 B
    u64*   key        = (u64*)(ws + 1146368);            // 67200 B
    ulonglong2*   ent = (ulonglong2*)(ws + 1213568);     // 8400*32*16 = 4.3 MB

    float* out = (float*)d_out;

    decode_kernel<<<(N_TOT + 255) / 256, 256, 0, stream>>>(
        score0, bbox0, kps0, score1, bbox1, kps1, score2, bbox2, kps2,
        logit, sig, box, kps, key, rank, cnt, validw, rowflag);
    rank_kernel<<<dim3(RT, RT), 256, 0, stream>>>(key, rank);
    scatter_kernel<<<33, 256, 0, stream>>>(rank, logit, sig, box, kps,
                                           s_logit, s_sig, s_box, s_kps, validw);
    pairs_kernel<<<dim3(MASK_WORDS, MASK_WORDS), 64, 0, stream>>>(s_logit, s_box, cnt, ent, rowflag);
    nms_kernel<<<1, 64, 0, stream>>>(rowflag, validw, cnt, ent, keep_words);
    output_kernel<<<33, 256, 0, stream>>>(s_sig, s_box, s_kps, keep_words, out);
}